// Round 4
// baseline (873.074 us; speedup 1.0000x reference)
//
#include <hip/hip_runtime.h>

#define NN   10000
#define FIN  4096
#define HID  1024
#define CO   20
#define EE   160000
#define ET   170000   // EE + NN (self loops appended)

typedef __bf16 bf16x8 __attribute__((ext_vector_type(8)));
typedef float  f32x4  __attribute__((ext_vector_type(4)));

__device__ __forceinline__ float bf2f(unsigned short u) {
    unsigned int x = ((unsigned int)u) << 16;
    float f; __builtin_memcpy(&f, &x, 4); return f;
}
__device__ __forceinline__ unsigned short f2bf(float f) {
    unsigned int x; __builtin_memcpy(&x, &f, 4);
    unsigned int r = (x + 0x7fffu + ((x >> 16) & 1u)) >> 16;
    return (unsigned short)r;
}
__device__ __forceinline__ void unpack4(int2 v, float* f) {
    unsigned int a = (unsigned int)v.x, b = (unsigned int)v.y;
    f[0] = bf2f((unsigned short)(a & 0xffffu)); f[1] = bf2f((unsigned short)(a >> 16));
    f[2] = bf2f((unsigned short)(b & 0xffffu)); f[3] = bf2f((unsigned short)(b >> 16));
}
__device__ __forceinline__ void unpack8(int4 v, float* f) {
    int2 lo; lo.x = v.x; lo.y = v.y;
    int2 hi; hi.x = v.z; hi.y = v.w;
    unpack4(lo, f); unpack4(hi, f + 4);
}
// edge accessor robust to int32 or int64 storage (is64 detected at runtime)
__device__ __forceinline__ int edge_at(const int* __restrict__ e, int idx, int is64) {
    return is64 ? e[2 * (size_t)idx] : e[idx];
}

// ---------------- dtype sniff: int64 edges have all-zero high words ----------------
__global__ void k_dtype(const int* __restrict__ edg, int* __restrict__ flag) {
    if (threadIdx.x == 0 && blockIdx.x == 0) {
        int z = 0;
        for (int j = 0; j < 64; j++) z |= edg[2 * j + 1];
        flag[0] = (z == 0) ? 1 : 0;
    }
}

// ---------------- fp32 -> bf16 cast (8 elems/thread, RTNE) ----------------
__global__ void k_cast(const float* __restrict__ src, unsigned short* __restrict__ dst,
                       int n8) {
    int i = blockIdx.x * 256 + threadIdx.x;
    if (i >= n8) return;
    const float4* s = (const float4*)src + (size_t)i * 2;
    float4 a = s[0], b = s[1];
    int4 o;
    o.x = (int)((unsigned)f2bf(a.x) | ((unsigned)f2bf(a.y) << 16));
    o.y = (int)((unsigned)f2bf(a.z) | ((unsigned)f2bf(a.w) << 16));
    o.z = (int)((unsigned)f2bf(b.x) | ((unsigned)f2bf(b.y) << 16));
    o.w = (int)((unsigned)f2bf(b.z) | ((unsigned)f2bf(b.w) << 16));
    *(int4*)(dst + (size_t)i * 8) = o;
}

// ---------------- init: zero counts and csr ----------------
__global__ void k_init(int* __restrict__ cnt, int* __restrict__ csr) {
    int i = blockIdx.x * 256 + threadIdx.x;
    if (i < NN) cnt[i] = 0;
    if (i < ET) csr[i] = 0;
}

// ---------------- folded attention vectors (fp32 weights) ----------------
// ws1v = Ws1^T @ as1 [FIN]; wd1v = Wd1^T @ ad1 [FIN]; wd2v = Wd2^T @ ad2 [HID]
__global__ void k_vecs(const float* __restrict__ Ws1, const float* __restrict__ Wd1,
                       const float* __restrict__ as1, const float* __restrict__ ad1,
                       const float* __restrict__ Wd2, const float* __restrict__ ad2,
                       float* __restrict__ ws1v, float* __restrict__ wd1v,
                       float* __restrict__ wd2v) {
    int k = blockIdx.x * 256 + threadIdx.x;
    if (k < FIN) {
        float s1 = 0.f, d1 = 0.f;
        for (int r = 0; r < HID; r++) {
            s1 += as1[r] * Ws1[(size_t)r * FIN + k];
            d1 += ad1[r] * Wd1[(size_t)r * FIN + k];
        }
        ws1v[k] = s1; wd1v[k] = d1;
    }
    if (k < HID) {
        float d2 = 0.f;
        for (int r = 0; r < CO; r++) d2 += ad2[r] * Wd2[(size_t)r * HID + k];
        wd2v[k] = d2;
    }
}

// ---------------- MFMA GEMM: C[M,N] = A[M,K] @ B[N,K]^T (bf16 in/out, fp32 acc) ----
#define GBM 128
#define GBN 128
#define GBK 32
#define GPAD 40

__global__ __launch_bounds__(256) void k_gemm_bt(
    const unsigned short* __restrict__ A, const unsigned short* __restrict__ B,
    unsigned short* __restrict__ C, int M, int Nn, int K) {
    __shared__ __bf16 As[GBM * GPAD];
    __shared__ __bf16 Bs[GBN * GPAD];
    int m0 = blockIdx.x * GBM;
    int n0 = blockIdx.y * GBN;
    int tid = threadIdx.x;
    int lane = tid & 63, wave = tid >> 6;
    int wm = (wave >> 1) * 64, wn = (wave & 1) * 64;
    int lrow = lane & 15, lk8 = (lane >> 4) * 8;

    f32x4 acc[4][4];
#pragma unroll
    for (int r = 0; r < 4; r++)
#pragma unroll
        for (int c = 0; c < 4; c++) acc[r][c] = (f32x4){0.f, 0.f, 0.f, 0.f};

    for (int k0 = 0; k0 < K; k0 += GBK) {
        __syncthreads();
#pragma unroll
        for (int i = 0; i < 2; i++) {
            int id = tid + i * 256;
            int r  = id >> 2;
            int kc = (id & 3) * 8;
            int gm = m0 + r; if (gm >= M) gm = M - 1;
            int gn = n0 + r; if (gn >= Nn) gn = Nn - 1;
            *(int4*)(&As[r * GPAD + kc]) = *(const int4*)(&A[(size_t)gm * K + k0 + kc]);
            *(int4*)(&Bs[r * GPAD + kc]) = *(const int4*)(&B[(size_t)gn * K + k0 + kc]);
        }
        __syncthreads();
        bf16x8 af[4], bfr[4];
#pragma unroll
        for (int r = 0; r < 4; r++)
            af[r] = *(const bf16x8*)(&As[(wm + r * 16 + lrow) * GPAD + lk8]);
#pragma unroll
        for (int c = 0; c < 4; c++)
            bfr[c] = *(const bf16x8*)(&Bs[(wn + c * 16 + lrow) * GPAD + lk8]);
#pragma unroll
        for (int r = 0; r < 4; r++)
#pragma unroll
            for (int c = 0; c < 4; c++)
                acc[r][c] = __builtin_amdgcn_mfma_f32_16x16x32_bf16(af[r], bfr[c], acc[r][c], 0, 0, 0);
    }
    int orow = (lane >> 4) * 4;
    int ocol = lane & 15;
#pragma unroll
    for (int r = 0; r < 4; r++)
#pragma unroll
        for (int c = 0; c < 4; c++)
#pragma unroll
            for (int i = 0; i < 4; i++) {
                int m = m0 + wm + r * 16 + orow + i;
                int n = n0 + wn + c * 16 + ocol;
                if (m < M) C[(size_t)m * Nn + n] = f2bf(acc[r][c][i]);
            }
}

// ---- per-node dots: a_src1, a_dst1, ms0 (one wave per node; xb bf16, weights fp32) ----
__global__ __launch_bounds__(256) void k_rowdots(
    const unsigned short* __restrict__ xb, const float* __restrict__ ws1v,
    const float* __restrict__ wd1v, const float* __restrict__ W0,
    const float* __restrict__ b0, float* __restrict__ a_src1,
    float* __restrict__ a_dst1, float* __restrict__ ms0) {
    int w = threadIdx.x >> 6, lane = threadIdx.x & 63;
    int n = blockIdx.x * 4 + w;
    if (n >= NN) return;
    float part[22];
#pragma unroll
    for (int v = 0; v < 22; v++) part[v] = 0.f;
    const unsigned short* xr = xb + (size_t)n * FIN;
#pragma unroll
    for (int i = 0; i < 8; i++) {
        int k = i * 512 + lane * 8;
        float xf[8];
        unpack8(*(const int4*)(xr + k), xf);
        {
            float4 a = *(const float4*)(ws1v + k), b = *(const float4*)(ws1v + k + 4);
            part[0] += xf[0]*a.x + xf[1]*a.y + xf[2]*a.z + xf[3]*a.w
                     + xf[4]*b.x + xf[5]*b.y + xf[6]*b.z + xf[7]*b.w;
        }
        {
            float4 a = *(const float4*)(wd1v + k), b = *(const float4*)(wd1v + k + 4);
            part[1] += xf[0]*a.x + xf[1]*a.y + xf[2]*a.z + xf[3]*a.w
                     + xf[4]*b.x + xf[5]*b.y + xf[6]*b.z + xf[7]*b.w;
        }
#pragma unroll
        for (int c = 0; c < CO; c++) {
            const float* wr = W0 + (size_t)c * FIN + k;
            float4 a = *(const float4*)wr, b = *(const float4*)(wr + 4);
            part[2 + c] += xf[0]*a.x + xf[1]*a.y + xf[2]*a.z + xf[3]*a.w
                         + xf[4]*b.x + xf[5]*b.y + xf[6]*b.z + xf[7]*b.w;
        }
    }
#pragma unroll
    for (int v = 0; v < 22; v++)
        for (int o = 32; o; o >>= 1) part[v] += __shfl_xor(part[v], o, 64);
    if (lane == 0) {
        a_src1[n] = part[0];
        a_dst1[n] = part[1];
        for (int c = 0; c < CO; c++) ms0[(size_t)n * CO + c] = part[2 + c] + b0[c];
    }
}

// ---------------- CSR build ----------------
__global__ void k_count(const int* __restrict__ edges, const int* __restrict__ flag,
                        int* __restrict__ cnt) {
    int k = blockIdx.x * 256 + threadIdx.x;
    if (k >= ET) return;
    int is64 = flag[0];
    int d = (k < EE) ? edge_at(edges, EE + k, is64) : (k - EE);
    if ((unsigned)d < NN) atomicAdd(&cnt[d], 1);
}

__global__ __launch_bounds__(1024) void k_scan(const int* __restrict__ cnt,
                                               int* __restrict__ offs,
                                               int* __restrict__ cursor) {
    __shared__ int buf[1024];
    __shared__ int carry_s;
    int t = threadIdx.x;
    if (t == 0) { carry_s = 0; offs[0] = 0; }
    __syncthreads();
    for (int base = 0; base < NN; base += 1024) {
        int i = base + t;
        int v = (i < NN) ? cnt[i] : 0;
        buf[t] = v;
        __syncthreads();
        for (int o = 1; o < 1024; o <<= 1) {
            int add = (t >= o) ? buf[t - o] : 0;
            __syncthreads();
            buf[t] += add;
            __syncthreads();
        }
        int incl = buf[t] + carry_s;
        if (i < NN) { offs[i + 1] = incl; cursor[i] = incl - v; }
        __syncthreads();
        if (t == 1023) carry_s += buf[1023];
        __syncthreads();
    }
}

__global__ void k_scatter(const int* __restrict__ edges, const int* __restrict__ flag,
                          int* __restrict__ cursor, int* __restrict__ csr_src) {
    int k = blockIdx.x * 256 + threadIdx.x;
    if (k >= ET) return;
    int is64 = flag[0];
    int s, d;
    if (k < EE) { s = edge_at(edges, k, is64); d = edge_at(edges, EE + k, is64); }
    else        { s = d = k - EE; }
    if ((unsigned)d >= NN) return;
    if ((unsigned)s >= NN) s = 0;
    int pos = atomicAdd(&cursor[d], 1);
    csr_src[pos] = s;
}

// ---------------- per-node edge softmax (one wave per node) ----------------
__global__ __launch_bounds__(64) void k_alpha(const int* __restrict__ offs,
                                              const int* __restrict__ csr,
                                              const float* __restrict__ a_src,
                                              const float* __restrict__ a_dst,
                                              float* __restrict__ alpha) {
    int n = blockIdx.x, lane = threadIdx.x;
    int b = offs[n], deg = offs[n + 1] - b;
    float ad = a_dst[n];
    float mymax = -INFINITY;
    for (int j = lane; j < deg; j += 64) {
        float v = a_src[csr[b + j]] + ad;
        v = (v >= 0.f) ? v : 0.2f * v;
        mymax = fmaxf(mymax, v);
    }
    for (int o = 32; o; o >>= 1) mymax = fmaxf(mymax, __shfl_xor(mymax, o, 64));
    float mysum = 0.f;
    for (int j = lane; j < deg; j += 64) {
        float v = a_src[csr[b + j]] + ad;
        v = (v >= 0.f) ? v : 0.2f * v;
        mysum += expf(v - mymax);
    }
    for (int o = 32; o; o >>= 1) mysum += __shfl_xor(mysum, o, 64);
    float inv = 1.0f / (mysum + 1e-16f);
    for (int j = lane; j < deg; j += 64) {
        float v = a_src[csr[b + j]] + ad;
        v = (v >= 0.f) ? v : 0.2f * v;
        alpha[b + j] = expf(v - mymax) * inv;
    }
}

// ------- fused: layer-1 agg + bias + ELU + H2/a_src2/a_dst2 (h never stored) -------
__global__ __launch_bounds__(256) void k_agg1f(
    const int* __restrict__ offs, const int* __restrict__ csr,
    const float* __restrict__ alpha, const unsigned short* __restrict__ H1,
    const float* __restrict__ b1, const float* __restrict__ Ws2,
    const float* __restrict__ wd2v, const float* __restrict__ as2,
    float* __restrict__ H2, float* __restrict__ a_src2, float* __restrict__ a_dst2) {
    int n = blockIdx.x, t = threadIdx.x, lane = t & 63, wv = t >> 6;
    int b = offs[n], deg = offs[n + 1] - b;
    float acc[4] = {0.f, 0.f, 0.f, 0.f};
    for (int j = 0; j < deg; j++) {
        int s = csr[b + j];
        float w = alpha[b + j];
        float f[4]; unpack4(*(const int2*)(H1 + (size_t)s * HID + t * 4), f);
        acc[0] += w * f[0]; acc[1] += w * f[1];
        acc[2] += w * f[2]; acc[3] += w * f[3];
    }
    float4 bb = *(const float4*)(b1 + t * 4);
    float xf[4];
    xf[0] = acc[0] + bb.x; xf[1] = acc[1] + bb.y;
    xf[2] = acc[2] + bb.z; xf[3] = acc[3] + bb.w;
#pragma unroll
    for (int i = 0; i < 4; i++)
        xf[i] = (xf[i] > 0.f) ? xf[i] : (expf(xf[i]) - 1.f);   // ELU in registers
    float part[21];
#pragma unroll
    for (int c = 0; c < CO; c++) {
        float4 wf = *(const float4*)(Ws2 + (size_t)c * HID + t * 4);
        part[c] = xf[0]*wf.x + xf[1]*wf.y + xf[2]*wf.z + xf[3]*wf.w;
    }
    {
        float4 w = *(const float4*)(wd2v + t * 4);
        part[20] = xf[0]*w.x + xf[1]*w.y + xf[2]*w.z + xf[3]*w.w;
    }
    __shared__ float red[21][4];
    __shared__ float dv[21];
#pragma unroll
    for (int v = 0; v < 21; v++) {
        float s = part[v];
        for (int o = 32; o; o >>= 1) s += __shfl_down(s, o, 64);
        if (lane == 0) red[v][wv] = s;
    }
    __syncthreads();
    if (t < 21) {
        float s = red[t][0] + red[t][1] + red[t][2] + red[t][3];
        dv[t] = s;
        if (t < CO) H2[(size_t)n * CO + t] = s;
        else        a_dst2[n] = s;
    }
    __syncthreads();
    if (t == 0) {
        float a = 0.f;
        for (int c = 0; c < CO; c++) a += dv[c] * as2[c];
        a_src2[n] = a;
    }
}

// ---------------- layer-2 aggregation + bias -> mil_score1 ----------------
__global__ __launch_bounds__(64) void k_agg2(const int* __restrict__ offs,
                                             const int* __restrict__ csr,
                                             const float* __restrict__ alpha,
                                             const float* __restrict__ H2,
                                             const float* __restrict__ b2,
                                             float* __restrict__ ms1) {
    int n = blockIdx.x, t = threadIdx.x;
    if (t >= CO) return;
    int b = offs[n], deg = offs[n + 1] - b;
    float acc = 0.f;
    for (int j = 0; j < deg; j++)
        acc += alpha[b + j] * H2[(size_t)csr[b + j] * CO + t];
    ms1[(size_t)n * CO + t] = acc + b2[t];
}

// ------- final: softmax over proposals (axis 0) * ms1 -> float32 out -------
__global__ __launch_bounds__(256) void k_final(const float* __restrict__ ms0,
                                               const float* __restrict__ ms1,
                                               float* __restrict__ out) {
    int c = blockIdx.x, t = threadIdx.x, lane = t & 63, wv = t >> 6;
    __shared__ float r4[4];
    __shared__ float bval;
    float m = -INFINITY;
    for (int n = t; n < NN; n += 256) m = fmaxf(m, ms0[(size_t)n * CO + c]);
    for (int o = 32; o; o >>= 1) m = fmaxf(m, __shfl_xor(m, o, 64));
    if (lane == 0) r4[wv] = m;
    __syncthreads();
    if (t == 0) bval = fmaxf(fmaxf(r4[0], r4[1]), fmaxf(r4[2], r4[3]));
    __syncthreads();
    float gmax = bval;
    __syncthreads();
    float s = 0.f;
    for (int n = t; n < NN; n += 256) s += expf(ms0[(size_t)n * CO + c] - gmax);
    for (int o = 32; o; o >>= 1) s += __shfl_xor(s, o, 64);
    if (lane == 0) r4[wv] = s;
    __syncthreads();
    if (t == 0) bval = r4[0] + r4[1] + r4[2] + r4[3];
    __syncthreads();
    float inv = 1.0f / bval;
    for (int n = t; n < NN; n += 256)
        out[(size_t)n * CO + c] =
            expf(ms0[(size_t)n * CO + c] - gmax) * inv * ms1[(size_t)n * CO + c];
}

// ------- new_edge output: float32, bf16-rounded to match bf16-cast reference -------
__global__ void k_edges(const int* __restrict__ edges, const int* __restrict__ flag,
                        float* __restrict__ out) {
    int k = blockIdx.x * 256 + threadIdx.x;
    if (k >= ET) return;
    int is64 = flag[0];
    int s, d;
    if (k < EE) { s = edge_at(edges, k, is64); d = edge_at(edges, EE + k, is64); }
    else        { s = d = k - EE; }
    out[NN * CO + k]      = bf2f(f2bf((float)s));
    out[NN * CO + ET + k] = bf2f(f2bf((float)d));
}

extern "C" void kernel_launch(void* const* d_in, const int* in_sizes, int n_in,
                              void* d_out, int out_size, void* d_ws, size_t ws_size,
                              hipStream_t stream) {
    const float* x   = (const float*)d_in[0];
    const int*   edg = (const int*)d_in[1];
    const float* W0  = (const float*)d_in[2];
    const float* b0  = (const float*)d_in[3];
    const float* Ws1 = (const float*)d_in[4];
    const float* Wd1 = (const float*)d_in[5];
    const float* as1 = (const float*)d_in[6];
    const float* ad1 = (const float*)d_in[7];
    const float* b1  = (const float*)d_in[8];
    const float* Ws2 = (const float*)d_in[9];
    const float* Wd2 = (const float*)d_in[10];
    const float* as2 = (const float*)d_in[11];
    const float* ad2 = (const float*)d_in[12];
    const float* b2  = (const float*)d_in[13];
    float* out = (float*)d_out;

    char* p = (char*)d_ws;
    auto alloc = [&](size_t bytes) -> char* {
        char* r = p; p += (bytes + 511) & ~((size_t)511); return r;
    };
    unsigned short* xb   = (unsigned short*)alloc((size_t)NN * FIN * 2);   // 81.9 MB
    unsigned short* Ws1b = (unsigned short*)alloc((size_t)HID * FIN * 2);  //  8.4 MB
    unsigned short* H1   = (unsigned short*)alloc((size_t)NN * HID * 2);   // 20.5 MB
    float* ms0    = (float*)alloc((size_t)NN * CO * 4);
    float* ms1    = (float*)alloc((size_t)NN * CO * 4);
    float* H2     = (float*)alloc((size_t)NN * CO * 4);
    float* ws1v   = (float*)alloc(FIN * 4);
    float* wd1v   = (float*)alloc(FIN * 4);
    float* wd2v   = (float*)alloc(HID * 4);
    float* a_src1 = (float*)alloc(NN * 4);
    float* a_dst1 = (float*)alloc(NN * 4);
    float* a_src2 = (float*)alloc(NN * 4);
    float* a_dst2 = (float*)alloc(NN * 4);
    float* alpha  = (float*)alloc((size_t)ET * 4);   // reused for layer 1 then layer 2
    int* csr_src  = (int*)alloc((size_t)ET * 4);
    int* cnt      = (int*)alloc(NN * 4);
    int* offs     = (int*)alloc((NN + 1) * 4);
    int* cursor   = (int*)alloc(NN * 4);
    int* eflag    = (int*)alloc(4 * 4);
    // total ~115 MB

    k_dtype<<<1, 64, 0, stream>>>(edg, eflag);
    k_init<<<(ET + 255) / 256, 256, 0, stream>>>(cnt, csr_src);
    k_cast<<<(NN * FIN / 8 + 255) / 256, 256, 0, stream>>>(x, xb, NN * FIN / 8);
    k_cast<<<(HID * FIN / 8 + 255) / 256, 256, 0, stream>>>(Ws1, Ws1b, HID * FIN / 8);
    k_vecs<<<FIN / 256, 256, 0, stream>>>(Ws1, Wd1, as1, ad1, Wd2, ad2, ws1v, wd1v, wd2v);
    dim3 gg((NN + GBM - 1) / GBM, HID / GBN);
    k_gemm_bt<<<gg, 256, 0, stream>>>(xb, Ws1b, H1, NN, HID, FIN);
    k_rowdots<<<(NN + 3) / 4, 256, 0, stream>>>(xb, ws1v, wd1v, W0, b0, a_src1, a_dst1, ms0);
    k_count<<<(ET + 255) / 256, 256, 0, stream>>>(edg, eflag, cnt);
    k_scan<<<1, 1024, 0, stream>>>(cnt, offs, cursor);
    k_scatter<<<(ET + 255) / 256, 256, 0, stream>>>(edg, eflag, cursor, csr_src);
    k_alpha<<<NN, 64, 0, stream>>>(offs, csr_src, a_src1, a_dst1, alpha);
    k_agg1f<<<NN, 256, 0, stream>>>(offs, csr_src, alpha, H1, b1, Ws2, wd2v, as2,
                                    H2, a_src2, a_dst2);
    k_alpha<<<NN, 64, 0, stream>>>(offs, csr_src, a_src2, a_dst2, alpha);
    k_agg2<<<NN, 64, 0, stream>>>(offs, csr_src, alpha, H2, b2, ms1);
    k_final<<<CO, 256, 0, stream>>>(ms0, ms1, out);
    k_edges<<<(ET + 255) / 256, 256, 0, stream>>>(edg, eflag, out);
}

// Round 5
// 697.169 us; speedup vs baseline: 1.2523x; 1.2523x over previous
//
#include <hip/hip_runtime.h>

#define NN   10000
#define FIN  4096
#define HID  1024
#define CO   20
#define EE   160000
#define ET   170000           // EE + NN (self loops appended)
#define NBV  (HID + 22)       // 1046 valid B rows: Ws1 | W0 | ws1v | wd1v

typedef __bf16 bf16x8 __attribute__((ext_vector_type(8)));
typedef float  f32x4  __attribute__((ext_vector_type(4)));

__device__ __forceinline__ float bf2f(unsigned short u) {
    unsigned int x = ((unsigned int)u) << 16;
    float f; __builtin_memcpy(&f, &x, 4); return f;
}
__device__ __forceinline__ unsigned short f2bf(float f) {
    unsigned int x; __builtin_memcpy(&x, &f, 4);
    unsigned int r = (x + 0x7fffu + ((x >> 16) & 1u)) >> 16;
    return (unsigned short)r;
}
__device__ __forceinline__ void unpack4(int2 v, float* f) {
    unsigned int a = (unsigned int)v.x, b = (unsigned int)v.y;
    f[0] = bf2f((unsigned short)(a & 0xffffu)); f[1] = bf2f((unsigned short)(a >> 16));
    f[2] = bf2f((unsigned short)(b & 0xffffu)); f[3] = bf2f((unsigned short)(b >> 16));
}
__device__ __forceinline__ int edge_at(const int* __restrict__ e, int idx, int is64) {
    return is64 ? e[2 * (size_t)idx] : e[idx];
}
__device__ __forceinline__ int4 pack8(float4 a, float4 b) {
    int4 o;
    o.x = (int)((unsigned)f2bf(a.x) | ((unsigned)f2bf(a.y) << 16));
    o.y = (int)((unsigned)f2bf(a.z) | ((unsigned)f2bf(a.w) << 16));
    o.z = (int)((unsigned)f2bf(b.x) | ((unsigned)f2bf(b.y) << 16));
    o.w = (int)((unsigned)f2bf(b.z) | ((unsigned)f2bf(b.w) << 16));
    return o;
}

// ---------------- dtype sniff (int64 edges -> all-zero high words) ----------------
__global__ void k_dtype(const int* __restrict__ edg, int* __restrict__ flag) {
    int v = edg[2 * threadIdx.x + 1];
    unsigned long long b = __ballot(v != 0);
    if (threadIdx.x == 0) flag[0] = (b == 0ull) ? 1 : 0;
}

// ---------------- fp32 -> bf16 cast (8 elems/thread) ----------------
__global__ void k_cast(const float* __restrict__ src, unsigned short* __restrict__ dst,
                       int n8) {
    int i = blockIdx.x * 256 + threadIdx.x;
    if (i >= n8) return;
    const float4* s = (const float4*)src + (size_t)i * 2;
    *(int4*)(dst + (size_t)i * 8) = pack8(s[0], s[1]);
}

// ---------------- init ----------------
__global__ void k_init(int* __restrict__ cnt, int* __restrict__ csr) {
    int i = blockIdx.x * 256 + threadIdx.x;
    if (i < NN) cnt[i] = 0;
    if (i < ET) csr[i] = 0;
}

// ---------------- attention-vector folds: partial sums over 128-row chunks ----------
__global__ __launch_bounds__(256) void k_vecs(const float* __restrict__ Ws1,
                                              const float* __restrict__ Wd1,
                                              const float* __restrict__ as1,
                                              const float* __restrict__ ad1,
                                              float* __restrict__ partS,
                                              float* __restrict__ partD) {
    int k = blockIdx.x * 256 + threadIdx.x;   // 0..4095
    int chunk = blockIdx.y;                   // 0..7
    int r0 = chunk * 128;
    float s = 0.f, d = 0.f;
    for (int r = r0; r < r0 + 128; r++) {
        s += as1[r] * Ws1[(size_t)r * FIN + k];
        d += ad1[r] * Wd1[(size_t)r * FIN + k];
    }
    partS[chunk * FIN + k] = s;
    partD[chunk * FIN + k] = d;
}

__global__ void k_vred(const float* __restrict__ partS, const float* __restrict__ partD,
                       const float* __restrict__ Wd2, const float* __restrict__ ad2,
                       float* __restrict__ ws1v, float* __restrict__ wd1v,
                       float* __restrict__ wd2v) {
    int k = blockIdx.x * 256 + threadIdx.x;
    if (k < FIN) {
        float s = 0.f, d = 0.f;
        for (int j = 0; j < 8; j++) { s += partS[j * FIN + k]; d += partD[j * FIN + k]; }
        ws1v[k] = s; wd1v[k] = d;
    }
    if (k < HID) {
        float d2 = 0.f;
        for (int r = 0; r < CO; r++) d2 += ad2[r] * Wd2[(size_t)r * HID + k];
        wd2v[k] = d2;
    }
}

// ------- build Bext [1046][4096] bf16: rows 0..1023 Ws1, 1024..1043 W0, 1044 ws1v, 1045 wd1v
__global__ void k_bext(const float* __restrict__ Ws1, const float* __restrict__ W0,
                       const float* __restrict__ ws1v, const float* __restrict__ wd1v,
                       unsigned short* __restrict__ Bext) {
    int i = blockIdx.x * 256 + threadIdx.x;
    if (i >= NBV * (FIN / 8)) return;
    int row = i >> 9;               // / 512
    int col = (i & 511) * 8;
    const float* src = (row < HID)      ? Ws1 + (size_t)row * FIN
                     : (row < HID + CO) ? W0 + (size_t)(row - HID) * FIN
                     : (row == HID + CO) ? ws1v : wd1v;
    const float4* s = (const float4*)(src + col);
    *(int4*)(Bext + (size_t)row * FIN + col) = pack8(s[0], s[1]);
}

// ---------------- MFMA GEMM w/ async global->LDS staging (m97 structure) ----------
// C[M, 1046] = xb @ Bext^T. Cols <HID -> H1 bf16 [M][HID]; cols HID..HID+21 -> ext fp32 [22][M].
#define GBM 128
#define GBN 128
#define GBK 32

__global__ __launch_bounds__(256) void k_gemm_ext(
    const unsigned short* __restrict__ A, const unsigned short* __restrict__ B,
    unsigned short* __restrict__ H1, float* __restrict__ ext, int M) {
    __shared__ __bf16 As[GBM * GBK];
    __shared__ __bf16 Bs[GBN * GBK];
    int n0 = blockIdx.x * GBN;          // n-tile fastest: A read ~once from HBM
    int m0 = blockIdx.y * GBM;
    int tid = threadIdx.x;
    int lane = tid & 63, wave = tid >> 6;
    int wm = (wave >> 1) * 64, wn = (wave & 1) * 64;
    int lrow = lane & 15, lk8 = (lane >> 4) * 8;

    // async staging geometry: wave covers 32 rows (2 instrs x 16 rows); lane -> (row, 16B chunk)
    int srow = lane >> 2;
    int scol = (lane & 3) * 8;
    int arow = wave * 32;
    int gmA0 = m0 + arow + srow;      if (gmA0 >= M) gmA0 = M - 1;
    int gmA1 = m0 + arow + 16 + srow; if (gmA1 >= M) gmA1 = M - 1;
    int gnB0 = n0 + arow + srow;      if (gnB0 >= NBV) gnB0 = NBV - 1;
    int gnB1 = n0 + arow + 16 + srow; if (gnB1 >= NBV) gnB1 = NBV - 1;
    const unsigned short* pA0 = A + (size_t)gmA0 * FIN + scol;
    const unsigned short* pA1 = A + (size_t)gmA1 * FIN + scol;
    const unsigned short* pB0 = B + (size_t)gnB0 * FIN + scol;
    const unsigned short* pB1 = B + (size_t)gnB1 * FIN + scol;
    __bf16* lA0 = &As[arow * GBK];
    __bf16* lA1 = &As[(arow + 16) * GBK];
    __bf16* lB0 = &Bs[arow * GBK];
    __bf16* lB1 = &Bs[(arow + 16) * GBK];

    f32x4 acc[4][4];
#pragma unroll
    for (int r = 0; r < 4; r++)
#pragma unroll
        for (int c = 0; c < 4; c++) acc[r][c] = (f32x4){0.f, 0.f, 0.f, 0.f};

    for (int k0 = 0; k0 < FIN; k0 += GBK) {
        __builtin_amdgcn_global_load_lds(
            (const __attribute__((address_space(1))) void*)(pA0 + k0),
            (__attribute__((address_space(3))) void*)lA0, 16, 0, 0);
        __builtin_amdgcn_global_load_lds(
            (const __attribute__((address_space(1))) void*)(pA1 + k0),
            (__attribute__((address_space(3))) void*)lA1, 16, 0, 0);
        __builtin_amdgcn_global_load_lds(
            (const __attribute__((address_space(1))) void*)(pB0 + k0),
            (__attribute__((address_space(3))) void*)lB0, 16, 0, 0);
        __builtin_amdgcn_global_load_lds(
            (const __attribute__((address_space(1))) void*)(pB1 + k0),
            (__attribute__((address_space(3))) void*)lB1, 16, 0, 0);
        __syncthreads();
        bf16x8 af[4], bfr[4];
#pragma unroll
        for (int r = 0; r < 4; r++)
            af[r] = *(const bf16x8*)(&As[(wm + r * 16 + lrow) * GBK + lk8]);
#pragma unroll
        for (int c = 0; c < 4; c++)
            bfr[c] = *(const bf16x8*)(&Bs[(wn + c * 16 + lrow) * GBK + lk8]);
#pragma unroll
        for (int r = 0; r < 4; r++)
#pragma unroll
            for (int c = 0; c < 4; c++)
                acc[r][c] = __builtin_amdgcn_mfma_f32_16x16x32_bf16(af[r], bfr[c], acc[r][c], 0, 0, 0);
        __syncthreads();
    }
    int orow = (lane >> 4) * 4, ocol = lane & 15;
#pragma unroll
    for (int r = 0; r < 4; r++)
#pragma unroll
        for (int c = 0; c < 4; c++)
#pragma unroll
            for (int i = 0; i < 4; i++) {
                int m = m0 + wm + r * 16 + orow + i;
                int n = n0 + wn + c * 16 + ocol;
                if (m < M) {
                    float v = acc[r][c][i];
                    if (n < HID)      H1[(size_t)m * HID + n] = f2bf(v);
                    else if (n < NBV) ext[(size_t)(n - HID) * NN + m] = v;
                }
            }
}

// ---------------- CSR build ----------------
__global__ void k_count(const int* __restrict__ edges, const int* __restrict__ flag,
                        int* __restrict__ cnt) {
    int k = blockIdx.x * 256 + threadIdx.x;
    if (k >= ET) return;
    int is64 = flag[0];
    int d = (k < EE) ? edge_at(edges, EE + k, is64) : (k - EE);
    if ((unsigned)d < NN) atomicAdd(&cnt[d], 1);
}

// 1024 threads x 10 elems each; shfl scan, 2 barriers
__global__ __launch_bounds__(1024) void k_scan(const int* __restrict__ cnt,
                                               int* __restrict__ offs,
                                               int* __restrict__ cursor) {
    int t = threadIdx.x, lane = t & 63, wv = t >> 6;
    int base = t * 10;
    int c[10]; int tot = 0;
    if (base < NN) {
#pragma unroll
        for (int j = 0; j < 10; j++) { c[j] = cnt[base + j]; tot += c[j]; }
    }
    int incl = tot;
#pragma unroll
    for (int o = 1; o < 64; o <<= 1) {
        int v = __shfl_up(incl, o, 64);
        if (lane >= o) incl += v;
    }
    __shared__ int wsum[16];
    if (lane == 63) wsum[wv] = incl;
    __syncthreads();
    if (t < 16) {
        int v = wsum[t];
        int inc2 = v;
#pragma unroll
        for (int o = 1; o < 16; o <<= 1) {
            int u = __shfl_up(inc2, o, 64);
            if (t >= o) inc2 += u;
        }
        wsum[t] = inc2 - v;  // exclusive wave offset
    }
    __syncthreads();
    int excl = incl - tot + wsum[wv];
    if (base < NN) {
        int run = excl;
#pragma unroll
        for (int j = 0; j < 10; j++) {
            cursor[base + j] = run;
            run += c[j];
            offs[base + j + 1] = run;
        }
    }
    if (t == 0) offs[0] = 0;
}

__global__ void k_scatter(const int* __restrict__ edges, const int* __restrict__ flag,
                          int* __restrict__ cursor, int* __restrict__ csr_src) {
    int k = blockIdx.x * 256 + threadIdx.x;
    if (k >= ET) return;
    int is64 = flag[0];
    int s, d;
    if (k < EE) { s = edge_at(edges, k, is64); d = edge_at(edges, EE + k, is64); }
    else        { s = d = k - EE; }
    if ((unsigned)d >= NN) return;
    if ((unsigned)s >= NN) s = 0;
    int pos = atomicAdd(&cursor[d], 1);
    csr_src[pos] = s;
}

// ---------------- per-node edge softmax (one wave per node) ----------------
__global__ __launch_bounds__(64) void k_alpha(const int* __restrict__ offs,
                                              const int* __restrict__ csr,
                                              const float* __restrict__ a_src,
                                              const float* __restrict__ a_dst,
                                              float* __restrict__ alpha) {
    int n = blockIdx.x, lane = threadIdx.x;
    int b = offs[n], deg = offs[n + 1] - b;
    float ad = a_dst[n];
    float mymax = -INFINITY;
    for (int j = lane; j < deg; j += 64) {
        float v = a_src[csr[b + j]] + ad;
        v = (v >= 0.f) ? v : 0.2f * v;
        mymax = fmaxf(mymax, v);
    }
    for (int o = 32; o; o >>= 1) mymax = fmaxf(mymax, __shfl_xor(mymax, o, 64));
    float mysum = 0.f;
    for (int j = lane; j < deg; j += 64) {
        float v = a_src[csr[b + j]] + ad;
        v = (v >= 0.f) ? v : 0.2f * v;
        mysum += expf(v - mymax);
    }
    for (int o = 32; o; o >>= 1) mysum += __shfl_xor(mysum, o, 64);
    float inv = 1.0f / (mysum + 1e-16f);
    for (int j = lane; j < deg; j += 64) {
        float v = a_src[csr[b + j]] + ad;
        v = (v >= 0.f) ? v : 0.2f * v;
        alpha[b + j] = expf(v - mymax) * inv;
    }
}

// ------- fused: layer-1 agg + bias + ELU + H2/a_src2/a_dst2 (h never stored) -------
__global__ __launch_bounds__(256) void k_agg1f(
    const int* __restrict__ offs, const int* __restrict__ csr,
    const float* __restrict__ alpha, const unsigned short* __restrict__ H1,
    const float* __restrict__ b1, const float* __restrict__ Ws2,
    const float* __restrict__ wd2v, const float* __restrict__ as2,
    float* __restrict__ H2, float* __restrict__ a_src2, float* __restrict__ a_dst2) {
    int n = blockIdx.x, t = threadIdx.x, lane = t & 63, wv = t >> 6;
    int b = offs[n], deg = offs[n + 1] - b;
    float acc[4] = {0.f, 0.f, 0.f, 0.f};
    for (int j = 0; j < deg; j++) {
        int s = csr[b + j];
        float w = alpha[b + j];
        float f[4]; unpack4(*(const int2*)(H1 + (size_t)s * HID + t * 4), f);
        acc[0] += w * f[0]; acc[1] += w * f[1];
        acc[2] += w * f[2]; acc[3] += w * f[3];
    }
    float4 bb = *(const float4*)(b1 + t * 4);
    float xf[4];
    xf[0] = acc[0] + bb.x; xf[1] = acc[1] + bb.y;
    xf[2] = acc[2] + bb.z; xf[3] = acc[3] + bb.w;
#pragma unroll
    for (int i = 0; i < 4; i++)
        xf[i] = (xf[i] > 0.f) ? xf[i] : (expf(xf[i]) - 1.f);
    float part[21];
#pragma unroll
    for (int c = 0; c < CO; c++) {
        float4 wf = *(const float4*)(Ws2 + (size_t)c * HID + t * 4);
        part[c] = xf[0]*wf.x + xf[1]*wf.y + xf[2]*wf.z + xf[3]*wf.w;
    }
    {
        float4 w = *(const float4*)(wd2v + t * 4);
        part[20] = xf[0]*w.x + xf[1]*w.y + xf[2]*w.z + xf[3]*w.w;
    }
    __shared__ float red[21][4];
    __shared__ float dv[21];
#pragma unroll
    for (int v = 0; v < 21; v++) {
        float s = part[v];
        for (int o = 32; o; o >>= 1) s += __shfl_down(s, o, 64);
        if (lane == 0) red[v][wv] = s;
    }
    __syncthreads();
    if (t < 21) {
        float s = red[t][0] + red[t][1] + red[t][2] + red[t][3];
        dv[t] = s;
        if (t < CO) H2[(size_t)n * CO + t] = s;
        else        a_dst2[n] = s;
    }
    __syncthreads();
    if (t == 0) {
        float a = 0.f;
        for (int c = 0; c < CO; c++) a += dv[c] * as2[c];
        a_src2[n] = a;
    }
}

// ---------------- layer-2 aggregation + bias -> ms1T [CO][NN] ----------------
__global__ __launch_bounds__(64) void k_agg2(const int* __restrict__ offs,
                                             const int* __restrict__ csr,
                                             const float* __restrict__ alpha,
                                             const float* __restrict__ H2,
                                             const float* __restrict__ b2,
                                             float* __restrict__ ms1T) {
    int n = blockIdx.x, t = threadIdx.x;
    if (t >= CO) return;
    int b = offs[n], deg = offs[n + 1] - b;
    float acc = 0.f;
    for (int j = 0; j < deg; j++)
        acc += alpha[b + j] * H2[(size_t)csr[b + j] * CO + t];
    ms1T[(size_t)t * NN + n] = acc + b2[t];
}

// ------- softmax stats per class (coalesced over ext rows) -------
__global__ __launch_bounds__(256) void k_fstat(const float* __restrict__ ext,
                                               float* __restrict__ gmax,
                                               float* __restrict__ ginv) {
    int c = blockIdx.x, t = threadIdx.x, lane = t & 63, wv = t >> 6;
    const float* row = ext + (size_t)c * NN;
    __shared__ float r4[4];
    __shared__ float bv;
    float m = -INFINITY;
    for (int n = t; n < NN; n += 256) m = fmaxf(m, row[n]);
    for (int o = 32; o; o >>= 1) m = fmaxf(m, __shfl_xor(m, o, 64));
    if (lane == 0) r4[wv] = m;
    __syncthreads();
    if (t == 0) bv = fmaxf(fmaxf(r4[0], r4[1]), fmaxf(r4[2], r4[3]));
    __syncthreads();
    float gm = bv;
    __syncthreads();
    float s = 0.f;
    for (int n = t; n < NN; n += 256) s += expf(row[n] - gm);
    for (int o = 32; o; o >>= 1) s += __shfl_xor(s, o, 64);
    if (lane == 0) r4[wv] = s;
    __syncthreads();
    if (t == 0) { gmax[c] = gm; ginv[c] = 1.0f / (r4[0] + r4[1] + r4[2] + r4[3]); }
}

// ------- out0[n][c] = exp(ms0-gmax)*ginv * ms1 (coalesced reads, float4 writes) -------
__global__ __launch_bounds__(256) void k_fout(const float* __restrict__ ext,
                                              const float* __restrict__ ms1T,
                                              const float* __restrict__ gmax,
                                              const float* __restrict__ ginv,
                                              float* __restrict__ out) {
    int n = blockIdx.x * 256 + threadIdx.x;
    if (n >= NN) return;
    float o[CO];
#pragma unroll
    for (int c = 0; c < CO; c++)
        o[c] = expf(ext[(size_t)c * NN + n] - gmax[c]) * ginv[c] * ms1T[(size_t)c * NN + n];
#pragma unroll
    for (int c = 0; c < CO; c += 4) {
        float4 v; v.x = o[c]; v.y = o[c + 1]; v.z = o[c + 2]; v.w = o[c + 3];
        *(float4*)(out + (size_t)n * CO + c) = v;
    }
}

// ------- new_edge output: fp32, bf16-rounded to match bf16-cast reference -------
__global__ void k_edges(const int* __restrict__ edges, const int* __restrict__ flag,
                        float* __restrict__ out) {
    int k = blockIdx.x * 256 + threadIdx.x;
    if (k >= ET) return;
    int is64 = flag[0];
    int s, d;
    if (k < EE) { s = edge_at(edges, k, is64); d = edge_at(edges, EE + k, is64); }
    else        { s = d = k - EE; }
    out[NN * CO + k]      = bf2f(f2bf((float)s));
    out[NN * CO + ET + k] = bf2f(f2bf((float)d));
}

extern "C" void kernel_launch(void* const* d_in, const int* in_sizes, int n_in,
                              void* d_out, int out_size, void* d_ws, size_t ws_size,
                              hipStream_t stream) {
    const float* x   = (const float*)d_in[0];
    const int*   edg = (const int*)d_in[1];
    const float* W0  = (const float*)d_in[2];
    const float* b1  = (const float*)d_in[8];
    const float* Ws1 = (const float*)d_in[4];
    const float* Wd1 = (const float*)d_in[5];
    const float* as1 = (const float*)d_in[6];
    const float* ad1 = (const float*)d_in[7];
    const float* Ws2 = (const float*)d_in[9];
    const float* Wd2 = (const float*)d_in[10];
    const float* as2 = (const float*)d_in[11];
    const float* ad2 = (const float*)d_in[12];
    const float* b2  = (const float*)d_in[13];
    float* out = (float*)d_out;

    char* p = (char*)d_ws;
    auto alloc = [&](size_t bytes) -> char* {
        char* r = p; p += (bytes + 511) & ~((size_t)511); return r;
    };
    unsigned short* xb   = (unsigned short*)alloc((size_t)NN * FIN * 2);   // 81.9 MB
    unsigned short* Bext = (unsigned short*)alloc((size_t)NBV * FIN * 2);  //  8.6 MB
    unsigned short* H1   = (unsigned short*)alloc((size_t)NN * HID * 2);   // 20.5 MB
    float* ext    = (float*)alloc((size_t)22 * NN * 4);   // ms0T rows 0..19, a_src1=20, a_dst1=21
    float* partS  = (float*)alloc((size_t)8 * FIN * 4);
    float* partD  = (float*)alloc((size_t)8 * FIN * 4);
    float* ws1v   = (float*)alloc(FIN * 4);
    float* wd1v   = (float*)alloc(FIN * 4);
    float* wd2v   = (float*)alloc(HID * 4);
    float* H2     = (float*)alloc((size_t)NN * CO * 4);
    float* ms1T   = (float*)alloc((size_t)CO * NN * 4);
    float* a_src2 = (float*)alloc(NN * 4);
    float* a_dst2 = (float*)alloc(NN * 4);
    float* alpha  = (float*)alloc((size_t)ET * 4);
    int* csr_src  = (int*)alloc((size_t)ET * 4);
    int* cnt      = (int*)alloc(NN * 4);
    int* offs     = (int*)alloc((NN + 1) * 4);
    int* cursor   = (int*)alloc(NN * 4);
    int* eflag    = (int*)alloc(64);
    float* gmax   = (float*)alloc(CO * 4);
    float* ginv   = (float*)alloc(CO * 4);

    k_dtype<<<1, 64, 0, stream>>>(edg, eflag);
    k_init<<<(ET + 255) / 256, 256, 0, stream>>>(cnt, csr_src);
    k_cast<<<(NN * FIN / 8 + 255) / 256, 256, 0, stream>>>(x, xb, NN * FIN / 8);
    dim3 vg(FIN / 256, 8);
    k_vecs<<<vg, 256, 0, stream>>>(Ws1, Wd1, as1, ad1, partS, partD);
    k_vred<<<FIN / 256, 256, 0, stream>>>(partS, partD, Wd2, ad2, ws1v, wd1v, wd2v);
    k_bext<<<(NBV * (FIN / 8) + 255) / 256, 256, 0, stream>>>(Ws1, W0, ws1v, wd1v, Bext);
    dim3 gg((NBV + GBN - 1) / GBN, (NN + GBM - 1) / GBM);   // n-tile fastest
    k_gemm_ext<<<gg, 256, 0, stream>>>(xb, Bext, H1, ext, NN);
    k_count<<<(ET + 255) / 256, 256, 0, stream>>>(edg, eflag, cnt);
    k_scan<<<1, 1024, 0, stream>>>(cnt, offs, cursor);
    k_scatter<<<(ET + 255) / 256, 256, 0, stream>>>(edg, eflag, cursor, csr_src);
    k_alpha<<<NN, 64, 0, stream>>>(offs, csr_src, ext + 20 * NN, ext + 21 * NN, alpha);
    k_agg1f<<<NN, 256, 0, stream>>>(offs, csr_src, alpha, H1, b1, Ws2, wd2v, as2,
                                    H2, a_src2, a_dst2);
    k_alpha<<<NN, 64, 0, stream>>>(offs, csr_src, a_src2, a_dst2, alpha);
    k_agg2<<<NN, 64, 0, stream>>>(offs, csr_src, alpha, H2, b2, ms1T);
    k_fstat<<<CO, 256, 0, stream>>>(ext, gmax, ginv);
    k_fout<<<(NN + 255) / 256, 256, 0, stream>>>(ext, ms1T, gmax, ginv, out);
    k_edges<<<(ET + 255) / 256, 256, 0, stream>>>(edg, eflag, out);
}

// Round 6
// 643.149 us; speedup vs baseline: 1.3575x; 1.0840x over previous
//
#include <hip/hip_runtime.h>

#define NN   10000
#define FIN  4096
#define HID  1024
#define CO   20
#define EE   160000
#define ET   170000           // EE + NN (self loops appended)
#define NBV  (HID + 22)       // 1046 valid B rows: Ws1 | W0 | ws1v | wd1v

typedef __bf16 bf16x8 __attribute__((ext_vector_type(8)));
typedef float  f32x4  __attribute__((ext_vector_type(4)));

__device__ __forceinline__ float bf2f(unsigned short u) {
    unsigned int x = ((unsigned int)u) << 16;
    float f; __builtin_memcpy(&f, &x, 4); return f;
}
__device__ __forceinline__ unsigned short f2bf(float f) {
    unsigned int x; __builtin_memcpy(&x, &f, 4);
    unsigned int r = (x + 0x7fffu + ((x >> 16) & 1u)) >> 16;
    return (unsigned short)r;
}
__device__ __forceinline__ void unpack4(int2 v, float* f) {
    unsigned int a = (unsigned int)v.x, b = (unsigned int)v.y;
    f[0] = bf2f((unsigned short)(a & 0xffffu)); f[1] = bf2f((unsigned short)(a >> 16));
    f[2] = bf2f((unsigned short)(b & 0xffffu)); f[3] = bf2f((unsigned short)(b >> 16));
}
__device__ __forceinline__ int edge_at(const int* __restrict__ e, int idx, int is64) {
    return is64 ? e[2 * (size_t)idx] : e[idx];
}
__device__ __forceinline__ int4 pack8(float4 a, float4 b) {
    int4 o;
    o.x = (int)((unsigned)f2bf(a.x) | ((unsigned)f2bf(a.y) << 16));
    o.y = (int)((unsigned)f2bf(a.z) | ((unsigned)f2bf(a.w) << 16));
    o.z = (int)((unsigned)f2bf(b.x) | ((unsigned)f2bf(b.y) << 16));
    o.w = (int)((unsigned)f2bf(b.z) | ((unsigned)f2bf(b.w) << 16));
    return o;
}

// ---------------- init counts + edge-dtype sniff (merged) ----------------
__global__ void k_initA(const int* __restrict__ edg, int* __restrict__ cnt,
                        int* __restrict__ flag) {
    int i = blockIdx.x * 256 + threadIdx.x;
    if (i < NN) cnt[i] = 0;
    if (blockIdx.x == 0 && threadIdx.x < 64) {
        int v = edg[2 * threadIdx.x + 1];
        unsigned long long b = __ballot(v != 0);
        if (threadIdx.x == 0) flag[0] = (b == 0ull) ? 1 : 0;
    }
}

// ---------------- fp32 -> bf16 cast (8 elems/thread) ----------------
__global__ void k_cast(const float* __restrict__ src, unsigned short* __restrict__ dst,
                       int n8) {
    int i = blockIdx.x * 256 + threadIdx.x;
    if (i >= n8) return;
    const float4* s = (const float4*)src + (size_t)i * 2;
    *(int4*)(dst + (size_t)i * 8) = pack8(s[0], s[1]);
}

// ---------------- attention-vector folds: partial sums over 128-row chunks ----------
__global__ __launch_bounds__(256) void k_vecs(const float* __restrict__ Ws1,
                                              const float* __restrict__ Wd1,
                                              const float* __restrict__ as1,
                                              const float* __restrict__ ad1,
                                              float* __restrict__ partS,
                                              float* __restrict__ partD) {
    int k = blockIdx.x * 256 + threadIdx.x;   // 0..4095
    int chunk = blockIdx.y;                   // 0..7
    int r0 = chunk * 128;
    float s = 0.f, d = 0.f;
    for (int r = r0; r < r0 + 128; r++) {
        s += as1[r] * Ws1[(size_t)r * FIN + k];
        d += ad1[r] * Wd1[(size_t)r * FIN + k];
    }
    partS[chunk * FIN + k] = s;
    partD[chunk * FIN + k] = d;
}

// reduce partials; write ws1v/wd1v straight into Bext rows 1044/1045; compute wd2v
__global__ void k_vred(const float* __restrict__ partS, const float* __restrict__ partD,
                       const float* __restrict__ Wd2, const float* __restrict__ ad2,
                       unsigned short* __restrict__ Bext, float* __restrict__ wd2v) {
    int k = blockIdx.x * 256 + threadIdx.x;
    if (k < FIN) {
        float s = 0.f, d = 0.f;
        for (int j = 0; j < 8; j++) { s += partS[j * FIN + k]; d += partD[j * FIN + k]; }
        Bext[(size_t)(HID + CO) * FIN + k]     = f2bf(s);
        Bext[(size_t)(HID + CO + 1) * FIN + k] = f2bf(d);
    }
    if (k < HID) {
        float d2 = 0.f;
        for (int r = 0; r < CO; r++) d2 += ad2[r] * Wd2[(size_t)r * HID + k];
        wd2v[k] = d2;
    }
}

// ------- build Bext rows 0..1043: Ws1 (1024) then W0 (20), bf16 ----------
__global__ void k_bext(const float* __restrict__ Ws1, const float* __restrict__ W0,
                       unsigned short* __restrict__ Bext) {
    int i = blockIdx.x * 256 + threadIdx.x;
    if (i >= (HID + CO) * (FIN / 8)) return;
    int row = i >> 9;               // / 512
    int col = (i & 511) * 8;
    const float* src = (row < HID) ? Ws1 + (size_t)row * FIN
                                   : W0 + (size_t)(row - HID) * FIN;
    const float4* s = (const float4*)(src + col);
    *(int4*)(Bext + (size_t)row * FIN + col) = pack8(s[0], s[1]);
}

// ---------------- MFMA GEMM, double-buffered async global->LDS staging ----------
// C[M, 1046] = xb @ Bext^T. Cols <HID -> H1 bf16 [M][HID]; cols HID..HID+21 -> ext fp32 [22][NN].
#define GBM 128
#define GBN 128
#define GBK 32

__global__ __launch_bounds__(256) void k_gemm_ext(
    const unsigned short* __restrict__ A, const unsigned short* __restrict__ B,
    unsigned short* __restrict__ H1, float* __restrict__ ext, int M) {
    __shared__ __bf16 As[2][GBM * GBK];
    __shared__ __bf16 Bs[2][GBN * GBK];
    int m0 = blockIdx.x * GBM;          // m fastest (round-4 empirical order)
    int n0 = blockIdx.y * GBN;
    int tid = threadIdx.x;
    int lane = tid & 63, wave = tid >> 6;
    int wm = (wave >> 1) * 64, wn = (wave & 1) * 64;
    int lrow = lane & 15, lk8 = (lane >> 4) * 8;

    // staging geometry: wave covers 32 rows (2 instrs x 16 rows); lane -> (row, 16B chunk)
    int srow = lane >> 2;
    int scol = (lane & 3) * 8;
    int arow = wave * 32;
    int gmA0 = m0 + arow + srow;      if (gmA0 >= M) gmA0 = M - 1;
    int gmA1 = m0 + arow + 16 + srow; if (gmA1 >= M) gmA1 = M - 1;
    int gnB0 = n0 + arow + srow;      if (gnB0 >= NBV) gnB0 = NBV - 1;
    int gnB1 = n0 + arow + 16 + srow; if (gnB1 >= NBV) gnB1 = NBV - 1;
    const unsigned short* pA0 = A + (size_t)gmA0 * FIN + scol;
    const unsigned short* pA1 = A + (size_t)gmA1 * FIN + scol;
    const unsigned short* pB0 = B + (size_t)gnB0 * FIN + scol;
    const unsigned short* pB1 = B + (size_t)gnB1 * FIN + scol;

    f32x4 acc[4][4];
#pragma unroll
    for (int r = 0; r < 4; r++)
#pragma unroll
        for (int c = 0; c < 4; c++) acc[r][c] = (f32x4){0.f, 0.f, 0.f, 0.f};

    auto stage = [&](int buf, int k0) {
        __builtin_amdgcn_global_load_lds(
            (const __attribute__((address_space(1))) void*)(pA0 + k0),
            (__attribute__((address_space(3))) void*)&As[buf][arow * GBK], 16, 0, 0);
        __builtin_amdgcn_global_load_lds(
            (const __attribute__((address_space(1))) void*)(pA1 + k0),
            (__attribute__((address_space(3))) void*)&As[buf][(arow + 16) * GBK], 16, 0, 0);
        __builtin_amdgcn_global_load_lds(
            (const __attribute__((address_space(1))) void*)(pB0 + k0),
            (__attribute__((address_space(3))) void*)&Bs[buf][arow * GBK], 16, 0, 0);
        __builtin_amdgcn_global_load_lds(
            (const __attribute__((address_space(1))) void*)(pB1 + k0),
            (__attribute__((address_space(3))) void*)&Bs[buf][(arow + 16) * GBK], 16, 0, 0);
    };

    stage(0, 0);                      // prefetch first tile
    int cur = 0;
    for (int k0 = 0; k0 < FIN; k0 += GBK) {
        __syncthreads();              // drains buf[cur] loads; MFMA of prev iter already overlapped them
        if (k0 + GBK < FIN) stage(cur ^ 1, k0 + GBK);   // next tile flies during MFMA below
        bf16x8 af[4], bfr[4];
#pragma unroll
        for (int r = 0; r < 4; r++)
            af[r] = *(const bf16x8*)(&As[cur][(wm + r * 16 + lrow) * GBK + lk8]);
#pragma unroll
        for (int c = 0; c < 4; c++)
            bfr[c] = *(const bf16x8*)(&Bs[cur][(wn + c * 16 + lrow) * GBK + lk8]);
#pragma unroll
        for (int r = 0; r < 4; r++)
#pragma unroll
            for (int c = 0; c < 4; c++)
                acc[r][c] = __builtin_amdgcn_mfma_f32_16x16x32_bf16(af[r], bfr[c], acc[r][c], 0, 0, 0);
        cur ^= 1;
    }
    int orow = (lane >> 4) * 4, ocol = lane & 15;
#pragma unroll
    for (int r = 0; r < 4; r++)
#pragma unroll
        for (int c = 0; c < 4; c++)
#pragma unroll
            for (int i = 0; i < 4; i++) {
                int m = m0 + wm + r * 16 + orow + i;
                int n = n0 + wn + c * 16 + ocol;
                if (m < M) {
                    float v = acc[r][c][i];
                    if (n < HID)      H1[(size_t)m * HID + n] = f2bf(v);
                    else if (n < NBV) ext[(size_t)(n - HID) * NN + m] = v;
                }
            }
}

// ---------------- CSR build ----------------
__global__ void k_count(const int* __restrict__ edges, const int* __restrict__ flag,
                        int* __restrict__ cnt) {
    int k = blockIdx.x * 256 + threadIdx.x;
    if (k >= ET) return;
    int is64 = flag[0];
    int d = (k < EE) ? edge_at(edges, EE + k, is64) : (k - EE);
    if ((unsigned)d < NN) atomicAdd(&cnt[d], 1);
}

// 1024 threads x 10 elems each; shfl scan, 2 barriers
__global__ __launch_bounds__(1024) void k_scan(const int* __restrict__ cnt,
                                               int* __restrict__ offs,
                                               int* __restrict__ cursor) {
    int t = threadIdx.x, lane = t & 63, wv = t >> 6;
    int base = t * 10;
    int c[10]; int tot = 0;
    if (base < NN) {
#pragma unroll
        for (int j = 0; j < 10; j++) { c[j] = cnt[base + j]; tot += c[j]; }
    }
    int incl = tot;
#pragma unroll
    for (int o = 1; o < 64; o <<= 1) {
        int v = __shfl_up(incl, o, 64);
        if (lane >= o) incl += v;
    }
    __shared__ int wsum[16];
    if (lane == 63) wsum[wv] = incl;
    __syncthreads();
    if (t < 16) {
        int v = wsum[t];
        int inc2 = v;
#pragma unroll
        for (int o = 1; o < 16; o <<= 1) {
            int u = __shfl_up(inc2, o, 64);
            if (t >= o) inc2 += u;
        }
        wsum[t] = inc2 - v;  // exclusive wave offset
    }
    __syncthreads();
    int excl = incl - tot + wsum[wv];
    if (base < NN) {
        int run = excl;
#pragma unroll
        for (int j = 0; j < 10; j++) {
            cursor[base + j] = run;
            run += c[j];
            offs[base + j + 1] = run;
        }
    }
    if (t == 0) offs[0] = 0;
}

__global__ void k_scatter(const int* __restrict__ edges, const int* __restrict__ flag,
                          int* __restrict__ cursor, int* __restrict__ csr_src) {
    int k = blockIdx.x * 256 + threadIdx.x;
    if (k >= ET) return;
    int is64 = flag[0];
    int s, d;
    if (k < EE) { s = edge_at(edges, k, is64); d = edge_at(edges, EE + k, is64); }
    else        { s = d = k - EE; }
    if ((unsigned)d >= NN) return;
    if ((unsigned)s >= NN) s = 0;
    int pos = atomicAdd(&cursor[d], 1);
    csr_src[pos] = s;
}

// ---------------- per-node edge softmax (one wave per node) ----------------
__global__ __launch_bounds__(64) void k_alpha(const int* __restrict__ offs,
                                              const int* __restrict__ csr,
                                              const float* __restrict__ a_src,
                                              const float* __restrict__ a_dst,
                                              float* __restrict__ alpha) {
    int n = blockIdx.x, lane = threadIdx.x;
    int b = offs[n], deg = offs[n + 1] - b;
    float ad = a_dst[n];
    float mymax = -INFINITY;
    for (int j = lane; j < deg; j += 64) {
        float v = a_src[csr[b + j]] + ad;
        v = (v >= 0.f) ? v : 0.2f * v;
        mymax = fmaxf(mymax, v);
    }
    for (int o = 32; o; o >>= 1) mymax = fmaxf(mymax, __shfl_xor(mymax, o, 64));
    float mysum = 0.f;
    for (int j = lane; j < deg; j += 64) {
        float v = a_src[csr[b + j]] + ad;
        v = (v >= 0.f) ? v : 0.2f * v;
        mysum += expf(v - mymax);
    }
    for (int o = 32; o; o >>= 1) mysum += __shfl_xor(mysum, o, 64);
    float inv = 1.0f / (mysum + 1e-16f);
    for (int j = lane; j < deg; j += 64) {
        float v = a_src[csr[b + j]] + ad;
        v = (v >= 0.f) ? v : 0.2f * v;
        alpha[b + j] = expf(v - mymax) * inv;
    }
}

// ------- fused: layer-1 agg + bias + ELU + H2/a_src2/a_dst2 (h never stored) -------
__global__ __launch_bounds__(256) void k_agg1f(
    const int* __restrict__ offs, const int* __restrict__ csr,
    const float* __restrict__ alpha, const unsigned short* __restrict__ H1,
    const float* __restrict__ b1, const float* __restrict__ Ws2,
    const float* __restrict__ wd2v, const float* __restrict__ as2,
    float* __restrict__ H2, float* __restrict__ a_src2, float* __restrict__ a_dst2) {
    int n = blockIdx.x, t = threadIdx.x, lane = t & 63, wv = t >> 6;
    int b = offs[n], deg = offs[n + 1] - b;
    float acc[4] = {0.f, 0.f, 0.f, 0.f};
    for (int j = 0; j < deg; j++) {
        int s = csr[b + j];
        float w = alpha[b + j];
        float f[4]; unpack4(*(const int2*)(H1 + (size_t)s * HID + t * 4), f);
        acc[0] += w * f[0]; acc[1] += w * f[1];
        acc[2] += w * f[2]; acc[3] += w * f[3];
    }
    float4 bb = *(const float4*)(b1 + t * 4);
    float xf[4];
    xf[0] = acc[0] + bb.x; xf[1] = acc[1] + bb.y;
    xf[2] = acc[2] + bb.z; xf[3] = acc[3] + bb.w;
#pragma unroll
    for (int i = 0; i < 4; i++)
        xf[i] = (xf[i] > 0.f) ? xf[i] : (expf(xf[i]) - 1.f);
    float part[21];
#pragma unroll
    for (int c = 0; c < CO; c++) {
        float4 wf = *(const float4*)(Ws2 + (size_t)c * HID + t * 4);
        part[c] = xf[0]*wf.x + xf[1]*wf.y + xf[2]*wf.z + xf[3]*wf.w;
    }
    {
        float4 w = *(const float4*)(wd2v + t * 4);
        part[20] = xf[0]*w.x + xf[1]*w.y + xf[2]*w.z + xf[3]*w.w;
    }
    __shared__ float red[21][4];
    __shared__ float dv[21];
#pragma unroll
    for (int v = 0; v < 21; v++) {
        float s = part[v];
        for (int o = 32; o; o >>= 1) s += __shfl_down(s, o, 64);
        if (lane == 0) red[v][wv] = s;
    }
    __syncthreads();
    if (t < 21) {
        float s = red[t][0] + red[t][1] + red[t][2] + red[t][3];
        dv[t] = s;
        if (t < CO) H2[(size_t)n * CO + t] = s;
        else        a_dst2[n] = s;
    }
    __syncthreads();
    if (t == 0) {
        float a = 0.f;
        for (int c = 0; c < CO; c++) a += dv[c] * as2[c];
        a_src2[n] = a;
    }
}

// ---------------- layer-2 aggregation + bias -> ms1T [CO][NN] ----------------
__global__ __launch_bounds__(64) void k_agg2(const int* __restrict__ offs,
                                             const int* __restrict__ csr,
                                             const float* __restrict__ alpha,
                                             const float* __restrict__ H2,
                                             const float* __restrict__ b2,
                                             float* __restrict__ ms1T) {
    int n = blockIdx.x, t = threadIdx.x;
    if (t >= CO) return;
    int b = offs[n], deg = offs[n + 1] - b;
    float acc = 0.f;
    for (int j = 0; j < deg; j++)
        acc += alpha[b + j] * H2[(size_t)csr[b + j] * CO + t];
    ms1T[(size_t)t * NN + n] = acc + b2[t];
}

// ------- softmax stats per class (coalesced over ext rows) -------
__global__ __launch_bounds__(256) void k_fstat(const float* __restrict__ ext,
                                               float* __restrict__ gmax,
                                               float* __restrict__ ginv) {
    int c = blockIdx.x, t = threadIdx.x, lane = t & 63, wv = t >> 6;
    const float* row = ext + (size_t)c * NN;
    __shared__ float r4[4];
    __shared__ float bv;
    float m = -INFINITY;
    for (int n = t; n < NN; n += 256) m = fmaxf(m, row[n]);
    for (int o = 32; o; o >>= 1) m = fmaxf(m, __shfl_xor(m, o, 64));
    if (lane == 0) r4[wv] = m;
    __syncthreads();
    if (t == 0) bv = fmaxf(fmaxf(r4[0], r4[1]), fmaxf(r4[2], r4[3]));
    __syncthreads();
    float gm = bv;
    __syncthreads();
    float s = 0.f;
    for (int n = t; n < NN; n += 256) s += expf(row[n] - gm);
    for (int o = 32; o; o >>= 1) s += __shfl_xor(s, o, 64);
    if (lane == 0) r4[wv] = s;
    __syncthreads();
    if (t == 0) { gmax[c] = gm; ginv[c] = 1.0f / (r4[0] + r4[1] + r4[2] + r4[3]); }
}

// ------- final out0 + new_edge in one kernel -------
__global__ __launch_bounds__(256) void k_fout(const float* __restrict__ ext,
                                              const float* __restrict__ ms1T,
                                              const float* __restrict__ gmax,
                                              const float* __restrict__ ginv,
                                              const int* __restrict__ edges,
                                              const int* __restrict__ flag,
                                              float* __restrict__ out) {
    int g = blockIdx.x * 256 + threadIdx.x;
    if (g < NN) {
        float o[CO];
#pragma unroll
        for (int c = 0; c < CO; c++)
            o[c] = expf(ext[(size_t)c * NN + g] - gmax[c]) * ginv[c] * ms1T[(size_t)c * NN + g];
#pragma unroll
        for (int c = 0; c < CO; c += 4) {
            float4 v; v.x = o[c]; v.y = o[c + 1]; v.z = o[c + 2]; v.w = o[c + 3];
            *(float4*)(out + (size_t)g * CO + c) = v;
        }
    }
    if (g < ET) {
        int is64 = flag[0];
        int s, d;
        if (g < EE) { s = edge_at(edges, g, is64); d = edge_at(edges, EE + g, is64); }
        else        { s = d = g - EE; }
        out[NN * CO + g]      = bf2f(f2bf((float)s));
        out[NN * CO + ET + g] = bf2f(f2bf((float)d));
    }
}

extern "C" void kernel_launch(void* const* d_in, const int* in_sizes, int n_in,
                              void* d_out, int out_size, void* d_ws, size_t ws_size,
                              hipStream_t stream) {
    const float* x   = (const float*)d_in[0];
    const int*   edg = (const int*)d_in[1];
    const float* W0  = (const float*)d_in[2];
    const float* Ws1 = (const float*)d_in[4];
    const float* Wd1 = (const float*)d_in[5];
    const float* as1 = (const float*)d_in[6];
    const float* ad1 = (const float*)d_in[7];
    const float* b1  = (const float*)d_in[8];
    const float* Ws2 = (const float*)d_in[9];
    const float* Wd2 = (const float*)d_in[10];
    const float* as2 = (const float*)d_in[11];
    const float* ad2 = (const float*)d_in[12];
    const float* b2  = (const float*)d_in[13];
    float* out = (float*)d_out;

    char* p = (char*)d_ws;
    auto alloc = [&](size_t bytes) -> char* {
        char* r = p; p += (bytes + 511) & ~((size_t)511); return r;
    };
    unsigned short* xb   = (unsigned short*)alloc((size_t)NN * FIN * 2);   // 81.9 MB
    unsigned short* Bext = (unsigned short*)alloc((size_t)NBV * FIN * 2);  //  8.6 MB
    unsigned short* H1   = (unsigned short*)alloc((size_t)NN * HID * 2);   // 20.5 MB
    float* ext    = (float*)alloc((size_t)22 * NN * 4);   // ms0T rows 0..19, a_src1=20, a_dst1=21
    float* partS  = (float*)alloc((size_t)8 * FIN * 4);
    float* partD  = (float*)alloc((size_t)8 * FIN * 4);
    float* wd2v   = (float*)alloc(HID * 4);
    float* H2     = (float*)alloc((size_t)NN * CO * 4);
    float* ms1T   = (float*)alloc((size_t)CO * NN * 4);
    float* a_src2 = (float*)alloc(NN * 4);
    float* a_dst2 = (float*)alloc(NN * 4);
    float* alpha  = (float*)alloc((size_t)ET * 4);
    int* csr_src  = (int*)alloc((size_t)ET * 4);
    int* cnt      = (int*)alloc(NN * 4);
    int* offs     = (int*)alloc((NN + 1) * 4);
    int* cursor   = (int*)alloc(NN * 4);
    int* eflag    = (int*)alloc(64);
    float* gmax   = (float*)alloc(CO * 4);
    float* ginv   = (float*)alloc(CO * 4);

    k_initA<<<(NN + 255) / 256, 256, 0, stream>>>(edg, cnt, eflag);
    k_cast<<<(NN * FIN / 8 + 255) / 256, 256, 0, stream>>>(x, xb, NN * FIN / 8);
    dim3 vg(FIN / 256, 8);
    k_vecs<<<vg, 256, 0, stream>>>(Ws1, Wd1, as1, ad1, partS, partD);
    k_vred<<<FIN / 256, 256, 0, stream>>>(partS, partD, Wd2, ad2, Bext, wd2v);
    k_bext<<<((HID + CO) * (FIN / 8) + 255) / 256, 256, 0, stream>>>(Ws1, W0, Bext);
    dim3 gg((NN + GBM - 1) / GBM, (NBV + GBN - 1) / GBN);   // m-tile fastest (round-4 order)
    k_gemm_ext<<<gg, 256, 0, stream>>>(xb, Bext, H1, ext, NN);
    k_count<<<(ET + 255) / 256, 256, 0, stream>>>(edg, eflag, cnt);
    k_scan<<<1, 1024, 0, stream>>>(cnt, offs, cursor);
    k_scatter<<<(ET + 255) / 256, 256, 0, stream>>>(edg, eflag, cursor, csr_src);
    k_fstat<<<CO, 256, 0, stream>>>(ext, gmax, ginv);
    k_alpha<<<NN, 64, 0, stream>>>(offs, csr_src, ext + 20 * NN, ext + 21 * NN, alpha);
    k_agg1f<<<NN, 256, 0, stream>>>(offs, csr_src, alpha, H1, b1, Ws2, wd2v, as2,
                                    H2, a_src2, a_dst2);
    k_alpha<<<NN, 64, 0, stream>>>(offs, csr_src, a_src2, a_dst2, alpha);
    k_agg2<<<NN, 64, 0, stream>>>(offs, csr_src, alpha, H2, b2, ms1T);
    k_fout<<<(ET + 255) / 256, 256, 0, stream>>>(ext, ms1T, gmax, ginv, edg, eflag, out);
}